// Round 1
// baseline (1209.337 us; speedup 1.0000x reference)
//
#include <hip/hip_runtime.h>
#include <math.h>

#define BB 16
#define TT 96
#define HH 31
#define WW 64
#define BT (BB*TT)
#define C1 16
#define C2 32
#define LH 64
#define NC 10

// ---------------------------------------------------------------------------
// K1: fused conv1 -> relu -> conv2 -> relu -> avgpool, one block per image,
// blockIdx.y = 0 real path / 1 imag path. conv1 output lives in LDS.
// LDS: s_c1[16][31][68] (x-padded, stride 68 floats = 272B, 16B-aligned rows)
//      + conv2 weights + pool accumulators = 153,600 B -> 1 block/CU, 8 waves.
// conv2 register blocking: 4 oc x 16 x accumulators -> 2.4 FMA per LDS byte
// (VALU-bound, not LDS-bound).
// ---------------------------------------------------------------------------
__global__ __launch_bounds__(512, 1)
void conv_pool_kernel(const float* __restrict__ xr, const float* __restrict__ xi,
                      const float* __restrict__ w1r, const float* __restrict__ b1r,
                      const float* __restrict__ w1i, const float* __restrict__ b1i,
                      const float* __restrict__ w2r, const float* __restrict__ b2r,
                      const float* __restrict__ w2i, const float* __restrict__ b2i,
                      float* __restrict__ pool_r, float* __restrict__ pool_m)
{
    __shared__ __align__(16) float s_c1[C1][HH][68];
    __shared__ __align__(16) float s_w2[C2*C1*9];
    __shared__ float s_b2[C2];
    __shared__ float s_pool[C2];

    const int tid  = threadIdx.x;
    const int img  = blockIdx.x;
    const int part = blockIdx.y;

    const float* xg = (part ? xi : xr) + img*(HH*WW);
    const float* w1 = part ? w1i : w1r;
    const float* b1 = part ? b1i : b1r;
    const float* w2 = part ? w2i : w2r;
    const float* b2 = part ? b2i : b2r;
    float* poolo = (part ? pool_m : pool_r) + img*C2;

    // stage conv2 weights, zero pool accumulators and pad columns
    for (int i = tid; i < C2*C1*9; i += 512) s_w2[i] = w2[i];
    if (tid < C2) { s_b2[tid] = b2[tid]; s_pool[tid] = 0.f; }
    for (int i = tid; i < C1*HH; i += 512) {
        int ch = i / HH, y = i % HH;
        s_c1[ch][y][0]  = 0.f;   // xp=0  (x=-1)
        s_c1[ch][y][65] = 0.f;   // xp=65 (x=64)
    }

    // conv1 (1 in-ch): tasks (ch, y, 16-wide x chunk). Input read via L1 (8KB image).
    for (int task = tid; task < C1*HH*4; task += 512) {
        int ch  = task / (HH*4);
        int rem = task % (HH*4);
        int y = rem >> 2, x0 = (rem & 3) * 16;
        float acc[16];
        float bb = b1[ch];
        #pragma unroll
        for (int j = 0; j < 16; ++j) acc[j] = bb;
        #pragma unroll
        for (int ky = 0; ky < 3; ++ky) {
            int row = y + ky - 1;
            if (row < 0 || row >= HH) continue;
            float in[18];
            #pragma unroll
            for (int j = 0; j < 18; ++j) {
                int xidx = x0 + j - 1;
                in[j] = (xidx >= 0 && xidx < WW) ? xg[row*WW + xidx] : 0.f;
            }
            float w0  = w1[ch*9 + ky*3 + 0];
            float w1v = w1[ch*9 + ky*3 + 1];
            float w2v = w1[ch*9 + ky*3 + 2];
            #pragma unroll
            for (int j = 0; j < 16; ++j)
                acc[j] += in[j]*w0 + in[j+1]*w1v + in[j+2]*w2v;
        }
        #pragma unroll
        for (int j = 0; j < 16; ++j)
            s_c1[ch][y][1 + x0 + j] = fmaxf(acc[j], 0.f);
    }

    __syncthreads();

    // conv2 + relu + pool: tasks (ocq of 4 ocs, y, 16-wide x chunk) = 8*31*4 = 992.
    // Task order oc-major -> lanes in a wave share ocq -> weight reads broadcast.
    for (int task = tid; task < 8*HH*4; task += 512) {
        int ocq = task / (HH*4);
        int rem = task % (HH*4);
        int y = rem >> 2, x0 = (rem & 3) * 16;
        float acc[4][16];
        #pragma unroll
        for (int o = 0; o < 4; ++o) {
            float bb = s_b2[ocq*4 + o];
            #pragma unroll
            for (int j = 0; j < 16; ++j) acc[o][j] = bb;
        }
        for (int ic = 0; ic < C1; ++ic) {
            #pragma unroll
            for (int ky = 0; ky < 3; ++ky) {
                int row = y + ky - 1;
                if (row < 0 || row >= HH) continue;
                const float* rp = &s_c1[ic][row][x0];   // xp = x0..x0+17 -> x = x0-1..x0+16
                float rr[18];
                *reinterpret_cast<float4*>(&rr[0])  = *reinterpret_cast<const float4*>(rp);
                *reinterpret_cast<float4*>(&rr[4])  = *reinterpret_cast<const float4*>(rp+4);
                *reinterpret_cast<float4*>(&rr[8])  = *reinterpret_cast<const float4*>(rp+8);
                *reinterpret_cast<float4*>(&rr[12]) = *reinterpret_cast<const float4*>(rp+12);
                *reinterpret_cast<float2*>(&rr[16]) = *reinterpret_cast<const float2*>(rp+16);
                int wb = ((ocq*4)*C1 + ic)*9 + ky*3;
                #pragma unroll
                for (int o = 0; o < 4; ++o) {
                    float w0  = s_w2[wb + o*C1*9 + 0];
                    float w1v = s_w2[wb + o*C1*9 + 1];
                    float w2v = s_w2[wb + o*C1*9 + 2];
                    #pragma unroll
                    for (int j = 0; j < 16; ++j)
                        acc[o][j] += rr[j]*w0 + rr[j+1]*w1v + rr[j+2]*w2v;
                }
            }
        }
        #pragma unroll
        for (int o = 0; o < 4; ++o) {
            float s = 0.f;
            #pragma unroll
            for (int j = 0; j < 16; ++j) s += fmaxf(acc[o][j], 0.f);
            atomicAdd(&s_pool[ocq*4 + o], s);
        }
    }

    __syncthreads();
    if (tid < C2) poolo[tid] = s_pool[tid] * (1.f/1984.f);
}

// ---------------------------------------------------------------------------
// K2: feat = [r, m, sqrt(r^2+m^2), atan2(m,r)] ; fused = relu(feat @ fus_w.T + b)
// 4 samples per block (256 thr = 4 x 64 outputs).
// ---------------------------------------------------------------------------
__global__ __launch_bounds__(256)
void feat_fused_kernel(const float* __restrict__ pool_r, const float* __restrict__ pool_m,
                       const float* __restrict__ fus_w, const float* __restrict__ fus_b,
                       float* __restrict__ fused)
{
    __shared__ __align__(16) float s_feat[4][128];
    int tid = threadIdx.x;
    int n0 = blockIdx.x * 4;
    if (tid < 128) {
        int s = tid >> 5, c = tid & 31;
        float r = pool_r[(n0+s)*C2 + c];
        float m = pool_m[(n0+s)*C2 + c];
        s_feat[s][c]      = r;
        s_feat[s][32 + c] = m;
        s_feat[s][64 + c] = sqrtf(r*r + m*m);
        s_feat[s][96 + c] = atan2f(m, r);
    }
    __syncthreads();
    int s = tid >> 6, k = tid & 63;
    float acc = fus_b[k];
    const float4* wv = reinterpret_cast<const float4*>(fus_w + k*128);
    const float4* fv = reinterpret_cast<const float4*>(&s_feat[s][0]);
    #pragma unroll
    for (int j = 0; j < 32; ++j) {
        float4 w = wv[j], f = fv[j];
        acc += w.x*f.x + w.y*f.y + w.z*f.z + w.w*f.w;
    }
    fused[(n0+s)*64 + k] = fmaxf(acc, 0.f);
}

// ---------------------------------------------------------------------------
// K3: LSTMs. Blocks 0..15: forward scan (96 steps) per sample, capture h at
// t==len-1. Blocks 16..31: backward LSTM collapses to a single step on
// fused[b, len-1] (hs_b[0] starts from zero state). Weights in registers
// (thread = gate row), x/h broadcast via LDS.
// ---------------------------------------------------------------------------
__device__ __forceinline__ float sigm(float x){ return 1.f/(1.f + expf(-x)); }

__global__ __launch_bounds__(256)
void lstm_kernel(const float* __restrict__ fused, const int* __restrict__ lengths,
                 const float* __restrict__ wf_ih, const float* __restrict__ wf_hh,
                 const float* __restrict__ bf_ih, const float* __restrict__ bf_hh,
                 const float* __restrict__ wb_ih, const float* __restrict__ wb_hh,
                 const float* __restrict__ bb_ih, const float* __restrict__ bb_hh,
                 float* __restrict__ last_f, float* __restrict__ hb0)
{
    __shared__ float s_x[64], s_h[64], s_c[64], s_g[256];
    const int g = threadIdx.x;           // gate row 0..255 (i|f|g|o blocks of 64)
    const int b = blockIdx.x & 15;
    const bool bwd = blockIdx.x >= 16;
    const int len = lengths[b];

    if (!bwd) {
        float wih[64], whh[64];
        const float* wi = wf_ih + g*64;
        const float* wh = wf_hh + g*64;
        #pragma unroll
        for (int j = 0; j < 64; j += 4) {
            float4 a = *reinterpret_cast<const float4*>(wi + j);
            wih[j]=a.x; wih[j+1]=a.y; wih[j+2]=a.z; wih[j+3]=a.w;
            float4 c = *reinterpret_cast<const float4*>(wh + j);
            whh[j]=c.x; whh[j+1]=c.y; whh[j+2]=c.z; whh[j+3]=c.w;
        }
        float bg = bf_ih[g] + bf_hh[g];
        if (g < 64) { s_h[g] = 0.f; s_c[g] = 0.f; }
        __syncthreads();
        for (int t = 0; t < TT; ++t) {
            if (g < 64) s_x[g] = fused[(b*TT + t)*64 + g];
            __syncthreads();
            float acc = bg;
            #pragma unroll
            for (int j = 0; j < 64; ++j) acc += s_x[j]*wih[j];
            #pragma unroll
            for (int j = 0; j < 64; ++j) acc += s_h[j]*whh[j];
            s_g[g] = acc;
            __syncthreads();
            if (g < 64) {
                float iv = sigm(s_g[g]);
                float fv = sigm(s_g[64+g]);
                float gv = tanhf(s_g[128+g]);
                float ov = sigm(s_g[192+g]);
                float c = fv*s_c[g] + iv*gv;
                float h = ov*tanhf(c);
                s_c[g] = c; s_h[g] = h;
                if (t == len-1) last_f[b*64+g] = h;
            }
            __syncthreads();
        }
    } else {
        float wih[64];
        const float* wi = wb_ih + g*64;
        #pragma unroll
        for (int j = 0; j < 64; j += 4) {
            float4 a = *reinterpret_cast<const float4*>(wi + j);
            wih[j]=a.x; wih[j+1]=a.y; wih[j+2]=a.z; wih[j+3]=a.w;
        }
        float bg = bb_ih[g] + bb_hh[g];
        if (g < 64) s_x[g] = fused[(b*TT + (len-1))*64 + g];
        __syncthreads();
        float acc = bg;
        #pragma unroll
        for (int j = 0; j < 64; ++j) acc += s_x[j]*wih[j];
        s_g[g] = acc;
        __syncthreads();
        if (g < 64) {
            float iv = sigm(s_g[g]);          // f gate irrelevant: c0 = 0
            float gv = tanhf(s_g[128+g]);
            float ov = sigm(s_g[192+g]);
            float c = iv*gv;
            float h = ov*tanhf(c);
            hb0[b*64+g] = h;
        }
    }
}

// ---------------------------------------------------------------------------
// K4: out[b,k] = fc_b[k] + last_f[b,:] . fc_w[k,0:64] + hb0[b,:] . fc_w[k,64:128]
// ---------------------------------------------------------------------------
__global__ __launch_bounds__(256)
void final_fc_kernel(const float* __restrict__ last_f, const float* __restrict__ hb0,
                     const float* __restrict__ fc_w, const float* __restrict__ fc_b,
                     float* __restrict__ out)
{
    int t = threadIdx.x;
    if (t >= BB*NC) return;
    int b = t / NC, k = t % NC;
    float acc = fc_b[k];
    const float* w = fc_w + k*128;
    #pragma unroll
    for (int j = 0; j < 64; ++j) acc += last_f[b*64+j]*w[j];
    #pragma unroll
    for (int j = 0; j < 64; ++j) acc += hb0[b*64+j]*w[64+j];
    out[b*NC + k] = acc;
}

extern "C" void kernel_launch(void* const* d_in, const int* in_sizes, int n_in,
                              void* d_out, int out_size, void* d_ws, size_t ws_size,
                              hipStream_t stream)
{
    const float* x_real = (const float*)d_in[0];
    const float* x_imag = (const float*)d_in[1];
    const int*   lengths= (const int*)d_in[2];
    const float* c1r_w = (const float*)d_in[3];
    const float* c1r_b = (const float*)d_in[4];
    const float* c1i_w = (const float*)d_in[5];
    const float* c1i_b = (const float*)d_in[6];
    const float* c2r_w = (const float*)d_in[7];
    const float* c2r_b = (const float*)d_in[8];
    const float* c2i_w = (const float*)d_in[9];
    const float* c2i_b = (const float*)d_in[10];
    const float* fus_w = (const float*)d_in[11];
    const float* fus_b = (const float*)d_in[12];
    const float* wf_ih = (const float*)d_in[13];
    const float* wf_hh = (const float*)d_in[14];
    const float* bf_ih = (const float*)d_in[15];
    const float* bf_hh = (const float*)d_in[16];
    const float* wb_ih = (const float*)d_in[17];
    const float* wb_hh = (const float*)d_in[18];
    const float* bb_ih = (const float*)d_in[19];
    const float* bb_hh = (const float*)d_in[20];
    const float* fc_w  = (const float*)d_in[21];
    const float* fc_b  = (const float*)d_in[22];
    float* out = (float*)d_out;

    // workspace layout (floats): pool_r | pool_m | fused | last_f | hb0  (~795 KB)
    float* ws     = (float*)d_ws;
    float* pool_r = ws;
    float* pool_m = pool_r + BT*C2;
    float* fusedb = pool_m + BT*C2;
    float* last_f = fusedb + BT*64;
    float* hb0    = last_f + BB*64;

    conv_pool_kernel<<<dim3(BT, 2), 512, 0, stream>>>(
        x_real, x_imag, c1r_w, c1r_b, c1i_w, c1i_b,
        c2r_w, c2r_b, c2i_w, c2i_b, pool_r, pool_m);

    feat_fused_kernel<<<BT/4, 256, 0, stream>>>(pool_r, pool_m, fus_w, fus_b, fusedb);

    lstm_kernel<<<32, 256, 0, stream>>>(fusedb, lengths,
        wf_ih, wf_hh, bf_ih, bf_hh, wb_ih, wb_hh, bb_ih, bb_hh, last_f, hb0);

    final_fc_kernel<<<1, 256, 0, stream>>>(last_f, hb0, fc_w, fc_b, out);
}

// Round 2
// 462.896 us; speedup vs baseline: 2.6125x; 2.6125x over previous
//
#include <hip/hip_runtime.h>
#include <math.h>

#define BB 16
#define TT 96
#define HH 31
#define WW 64
#define BT (BB*TT)
#define C1 16
#define C2 32
#define LH 64
#define NC 10

typedef _Float16 half8 __attribute__((ext_vector_type(8)));
typedef float floatx16 __attribute__((ext_vector_type(16)));

// padded conv1-output geometry: yp in [0,32] (y=-1..31), xp in [0,65] (x=-1..64)
#define XPAD 66
#define YPAD 33
#define NPOS (YPAD*XPAD)            // 2178 positions
#define SXBYTES (NPOS*32 + 128)     // 32B per position (16ch fp16) + swizzle pad

// XOR-swizzle: spread the 32B-stride position layout across LDS bank groups.
// Applied identically on write and read (involution on both sides).
__device__ __forceinline__ int swz(int byte) {
    return byte ^ (((byte >> 7) & 7) << 4);
}

// ---------------------------------------------------------------------------
// K1: conv1(fp32, SGPR weights) -> relu -> LDS fp16 channel-last ->
//     conv2 as 9 tap-GEMMs on v_mfma_f32_32x32x16_f16 -> relu -> avgpool.
// One block (256 thr, 4 waves) per (image, real/imag) pair. 2 blocks/CU.
// MFMA mapping per tap (ky,kx), N-tile of 32 positions (y fixed, x0..x0+31):
//   A: lane l holds W2[oc=l&31][ic=8*(l>>5)+i]          (regs, loaded once)
//   B: lane l holds X[ic=8*(l>>5)+i][pos=tile+ (l&31)]  (one ds_read_b128)
//   C: col=lane&31 (position), row(oc)=(r&3)+8*(r>>2)+4*(l>>5)
// ---------------------------------------------------------------------------
__global__ __launch_bounds__(256, 2)
void conv_pool_mfma(const float* __restrict__ xr, const float* __restrict__ xi,
                    const float* __restrict__ w1r, const float* __restrict__ b1r,
                    const float* __restrict__ w1i, const float* __restrict__ b1i,
                    const float* __restrict__ w2r, const float* __restrict__ b2r,
                    const float* __restrict__ w2i, const float* __restrict__ b2i,
                    float* __restrict__ pool_r, float* __restrict__ pool_m)
{
    __shared__ __align__(128) unsigned char s_x[SXBYTES];
    __shared__ float s_pool[C2];

    const int tid  = threadIdx.x;
    const int lane = tid & 63;
    const int img  = blockIdx.x;
    const int part = blockIdx.y;

    const float* xg = (part ? xi : xr) + img*(HH*WW);
    const float* w1 = part ? w1i : w1r;
    const float* b1 = part ? b1i : b1r;
    const float* w2 = part ? w2i : w2r;
    const float* b2 = part ? b2i : b2r;
    float* poolo = (part ? pool_m : pool_r) + img*C2;

    // zero whole LDS tile (borders stay zero = conv padding)
    for (int i = tid*16; i < SXBYTES; i += 256*16)
        *reinterpret_cast<int4*>(s_x + i) = make_int4(0,0,0,0);
    if (tid < C2) s_pool[tid] = 0.f;
    __syncthreads();

    // ---- conv1: thread = one output position, all 16 channels ----
    for (int p = tid; p < HH*WW; p += 256) {
        int y = p >> 6, x = p & 63;
        float a[16];
        #pragma unroll
        for (int ch = 0; ch < 16; ++ch) a[ch] = b1[ch];
        #pragma unroll
        for (int ky = 0; ky < 3; ++ky) {
            int row = y + ky - 1;
            #pragma unroll
            for (int kx = 0; kx < 3; ++kx) {
                int col = x + kx - 1;
                float v = (row >= 0 && row < HH && col >= 0 && col < WW)
                            ? xg[row*WW + col] : 0.f;
                #pragma unroll
                for (int ch = 0; ch < 16; ++ch)
                    a[ch] += v * w1[ch*9 + ky*3 + kx];   // uniform weight -> SGPR
            }
        }
        half8 lo, hi;
        #pragma unroll
        for (int ch = 0; ch < 8; ++ch) {
            lo[ch] = (_Float16)fmaxf(a[ch],     0.f);
            hi[ch] = (_Float16)fmaxf(a[8 + ch], 0.f);
        }
        int pos = (y + 1)*XPAD + (x + 1);
        *reinterpret_cast<half8*>(s_x + swz(pos*32))      = lo;
        *reinterpret_cast<half8*>(s_x + swz(pos*32 + 16)) = hi;
    }

    // ---- conv2 A-fragments + bias (global, L2-resident, once per block) ----
    const int oc  = lane & 31;
    const int icb = (lane >> 5) * 8;
    half8 af[9];
    #pragma unroll
    for (int t = 0; t < 9; ++t) {
        half8 v;
        #pragma unroll
        for (int i = 0; i < 8; ++i)
            v[i] = (_Float16)w2[(oc*C1 + icb + i)*9 + t];
        af[t] = v;
    }
    float bias[16];
    #pragma unroll
    for (int r = 0; r < 16; ++r)
        bias[r] = b2[(r & 3) + 8*(r >> 2) + 4*(lane >> 5)];

    __syncthreads();

    // ---- conv2 + relu + pool: 62 N-tiles of 32 positions, striped by wave ----
    float pool[16];
    #pragma unroll
    for (int r = 0; r < 16; ++r) pool[r] = 0.f;

    const int wav = tid >> 6;
    const int halfoff = (lane >> 5) << 4;
    for (int tile = wav; tile < 62; tile += 4) {
        int y  = tile >> 1;
        int x0 = (tile & 1) * 32;
        floatx16 acc;
        #pragma unroll
        for (int r = 0; r < 16; ++r) acc[r] = bias[r];
        int pbase = y*XPAD + x0 + (lane & 31);      // pos at (ky,kx)=(0,0)
        #pragma unroll
        for (int ky = 0; ky < 3; ++ky) {
            #pragma unroll
            for (int kx = 0; kx < 3; ++kx) {
                int pos = pbase + ky*XPAD + kx;
                half8 b = *reinterpret_cast<const half8*>(s_x + swz(pos*32 + halfoff));
                acc = __builtin_amdgcn_mfma_f32_32x32x16_f16(af[ky*3+kx], b, acc, 0, 0, 0);
            }
        }
        #pragma unroll
        for (int r = 0; r < 16; ++r) pool[r] += fmaxf(acc[r], 0.f);
    }

    // reduce positions across the 32-lane half (butterfly), then across waves
    #pragma unroll
    for (int m = 1; m <= 16; m <<= 1) {
        #pragma unroll
        for (int r = 0; r < 16; ++r) pool[r] += __shfl_xor(pool[r], m, 64);
    }
    if ((lane & 31) == 0) {
        #pragma unroll
        for (int r = 0; r < 16; ++r)
            atomicAdd(&s_pool[(r & 3) + 8*(r >> 2) + 4*(lane >> 5)], pool[r]);
    }
    __syncthreads();
    if (tid < C2) poolo[tid] = s_pool[tid] * (1.f/1984.f);
}

// ---------------------------------------------------------------------------
// K2: feat = [r, m, sqrt(r^2+m^2), atan2(m,r)] ; fused = relu(feat @ fus_w.T + b)
// ---------------------------------------------------------------------------
__global__ __launch_bounds__(256)
void feat_fused_kernel(const float* __restrict__ pool_r, const float* __restrict__ pool_m,
                       const float* __restrict__ fus_w, const float* __restrict__ fus_b,
                       float* __restrict__ fused)
{
    __shared__ __align__(16) float s_feat[4][128];
    int tid = threadIdx.x;
    int n0 = blockIdx.x * 4;
    if (tid < 128) {
        int s = tid >> 5, c = tid & 31;
        float r = pool_r[(n0+s)*C2 + c];
        float m = pool_m[(n0+s)*C2 + c];
        s_feat[s][c]      = r;
        s_feat[s][32 + c] = m;
        s_feat[s][64 + c] = sqrtf(r*r + m*m);
        s_feat[s][96 + c] = atan2f(m, r);
    }
    __syncthreads();
    int s = tid >> 6, k = tid & 63;
    float acc = fus_b[k];
    const float4* wv = reinterpret_cast<const float4*>(fus_w + k*128);
    const float4* fv = reinterpret_cast<const float4*>(&s_feat[s][0]);
    #pragma unroll
    for (int j = 0; j < 32; ++j) {
        float4 w = wv[j], f = fv[j];
        acc += w.x*f.x + w.y*f.y + w.z*f.z + w.w*f.w;
    }
    fused[(n0+s)*64 + k] = fmaxf(acc, 0.f);
}

// ---------------------------------------------------------------------------
// K3: LSTMs. Blocks 0..15: forward 96-step scan, capture h at t==len-1.
// Blocks 16..31: backward LSTM = single step on fused[b, len-1] (zero state).
// ---------------------------------------------------------------------------
__device__ __forceinline__ float sigm(float x){ return 1.f/(1.f + expf(-x)); }

__global__ __launch_bounds__(256)
void lstm_kernel(const float* __restrict__ fused, const int* __restrict__ lengths,
                 const float* __restrict__ wf_ih, const float* __restrict__ wf_hh,
                 const float* __restrict__ bf_ih, const float* __restrict__ bf_hh,
                 const float* __restrict__ wb_ih, const float* __restrict__ wb_hh,
                 const float* __restrict__ bb_ih, const float* __restrict__ bb_hh,
                 float* __restrict__ last_f, float* __restrict__ hb0)
{
    __shared__ float s_x[64], s_h[64], s_c[64], s_g[256];
    const int g = threadIdx.x;           // gate row 0..255 (i|f|g|o blocks of 64)
    const int b = blockIdx.x & 15;
    const bool bwd = blockIdx.x >= 16;
    const int len = lengths[b];

    if (!bwd) {
        float wih[64], whh[64];
        const float* wi = wf_ih + g*64;
        const float* wh = wf_hh + g*64;
        #pragma unroll
        for (int j = 0; j < 64; j += 4) {
            float4 a = *reinterpret_cast<const float4*>(wi + j);
            wih[j]=a.x; wih[j+1]=a.y; wih[j+2]=a.z; wih[j+3]=a.w;
            float4 c = *reinterpret_cast<const float4*>(wh + j);
            whh[j]=c.x; whh[j+1]=c.y; whh[j+2]=c.z; whh[j+3]=c.w;
        }
        float bg = bf_ih[g] + bf_hh[g];
        if (g < 64) { s_h[g] = 0.f; s_c[g] = 0.f; }
        __syncthreads();
        for (int t = 0; t < TT; ++t) {
            if (g < 64) s_x[g] = fused[(b*TT + t)*64 + g];
            __syncthreads();
            float acc = bg;
            #pragma unroll
            for (int j = 0; j < 64; ++j) acc += s_x[j]*wih[j];
            #pragma unroll
            for (int j = 0; j < 64; ++j) acc += s_h[j]*whh[j];
            s_g[g] = acc;
            __syncthreads();
            if (g < 64) {
                float iv = sigm(s_g[g]);
                float fv = sigm(s_g[64+g]);
                float gv = tanhf(s_g[128+g]);
                float ov = sigm(s_g[192+g]);
                float c = fv*s_c[g] + iv*gv;
                float h = ov*tanhf(c);
                s_c[g] = c; s_h[g] = h;
                if (t == len-1) last_f[b*64+g] = h;
            }
            __syncthreads();
        }
    } else {
        float wih[64];
        const float* wi = wb_ih + g*64;
        #pragma unroll
        for (int j = 0; j < 64; j += 4) {
            float4 a = *reinterpret_cast<const float4*>(wi + j);
            wih[j]=a.x; wih[j+1]=a.y; wih[j+2]=a.z; wih[j+3]=a.w;
        }
        float bg = bb_ih[g] + bb_hh[g];
        if (g < 64) s_x[g] = fused[(b*TT + (len-1))*64 + g];
        __syncthreads();
        float acc = bg;
        #pragma unroll
        for (int j = 0; j < 64; ++j) acc += s_x[j]*wih[j];
        s_g[g] = acc;
        __syncthreads();
        if (g < 64) {
            float iv = sigm(s_g[g]);          // f gate irrelevant: c0 = 0
            float gv = tanhf(s_g[128+g]);
            float ov = sigm(s_g[192+g]);
            float c = iv*gv;
            float h = ov*tanhf(c);
            hb0[b*64+g] = h;
        }
    }
}

// ---------------------------------------------------------------------------
// K4: out[b,k] = fc_b[k] + last_f[b,:].fc_w[k,0:64] + hb0[b,:].fc_w[k,64:128]
// ---------------------------------------------------------------------------
__global__ __launch_bounds__(256)
void final_fc_kernel(const float* __restrict__ last_f, const float* __restrict__ hb0,
                     const float* __restrict__ fc_w, const float* __restrict__ fc_b,
                     float* __restrict__ out)
{
    int t = threadIdx.x;
    if (t >= BB*NC) return;
    int b = t / NC, k = t % NC;
    float acc = fc_b[k];
    const float* w = fc_w + k*128;
    #pragma unroll
    for (int j = 0; j < 64; ++j) acc += last_f[b*64+j]*w[j];
    #pragma unroll
    for (int j = 0; j < 64; ++j) acc += hb0[b*64+j]*w[64+j];
    out[b*NC + k] = acc;
}

extern "C" void kernel_launch(void* const* d_in, const int* in_sizes, int n_in,
                              void* d_out, int out_size, void* d_ws, size_t ws_size,
                              hipStream_t stream)
{
    const float* x_real = (const float*)d_in[0];
    const float* x_imag = (const float*)d_in[1];
    const int*   lengths= (const int*)d_in[2];
    const float* c1r_w = (const float*)d_in[3];
    const float* c1r_b = (const float*)d_in[4];
    const float* c1i_w = (const float*)d_in[5];
    const float* c1i_b = (const float*)d_in[6];
    const float* c2r_w = (const float*)d_in[7];
    const float* c2r_b = (const float*)d_in[8];
    const float* c2i_w = (const float*)d_in[9];
    const float* c2i_b = (const float*)d_in[10];
    const float* fus_w = (const float*)d_in[11];
    const float* fus_b = (const float*)d_in[12];
    const float* wf_ih = (const float*)d_in[13];
    const float* wf_hh = (const float*)d_in[14];
    const float* bf_ih = (const float*)d_in[15];
    const float* bf_hh = (const float*)d_in[16];
    const float* wb_ih = (const float*)d_in[17];
    const float* wb_hh = (const float*)d_in[18];
    const float* bb_ih = (const float*)d_in[19];
    const float* bb_hh = (const float*)d_in[20];
    const float* fc_w  = (const float*)d_in[21];
    const float* fc_b  = (const float*)d_in[22];
    float* out = (float*)d_out;

    // workspace layout (floats): pool_r | pool_m | fused | last_f | hb0
    float* ws     = (float*)d_ws;
    float* pool_r = ws;
    float* pool_m = pool_r + BT*C2;
    float* fusedb = pool_m + BT*C2;
    float* last_f = fusedb + BT*64;
    float* hb0    = last_f + BB*64;

    conv_pool_mfma<<<dim3(BT, 2), 256, 0, stream>>>(
        x_real, x_imag, c1r_w, c1r_b, c1i_w, c1i_b,
        c2r_w, c2r_b, c2i_w, c2i_b, pool_r, pool_m);

    feat_fused_kernel<<<BT/4, 256, 0, stream>>>(pool_r, pool_m, fus_w, fus_b, fusedb);

    lstm_kernel<<<32, 256, 0, stream>>>(fusedb, lengths,
        wf_ih, wf_hh, bf_ih, bf_hh, wb_ih, wb_hh, bb_ih, bb_hh, last_f, hb0);

    final_fc_kernel<<<1, 256, 0, stream>>>(last_f, hb0, fc_w, fc_b, out);
}

// Round 3
// 357.384 us; speedup vs baseline: 3.3839x; 1.2952x over previous
//
#include <hip/hip_runtime.h>
#include <math.h>

#define BB 16
#define TT 96
#define HH 31
#define WW 64
#define BT (BB*TT)
#define C1 16
#define C2 32
#define LH 64
#define NC 10

typedef _Float16 half8 __attribute__((ext_vector_type(8)));
typedef float floatx16 __attribute__((ext_vector_type(16)));

// padded conv1-output geometry: yp in [0,32] (y=-1..31), xp in [0,65] (x=-1..64)
#define XPAD 66
#define YPAD 33
#define NPOS (YPAD*XPAD)            // 2178 positions
#define SXBYTES (NPOS*32 + 128)     // 32B per position (16ch fp16) + swizzle pad

// XOR-swizzle: spread the 32B-stride position layout across LDS bank groups.
// Applied identically on write and read.
__device__ __forceinline__ int swz(int byte) {
    return byte ^ (((byte >> 7) & 7) << 4);
}

// ---------------------------------------------------------------------------
// K1: conv1(fp32) -> relu -> LDS fp16 channel-last -> conv2 as 9 tap-GEMMs on
// v_mfma_f32_32x32x16_f16 -> relu -> avgpool.
// 512 thr (8 waves) per (image, part) block; 70KB LDS -> 2 blocks/CU
// -> 4 waves/SIMD (2x round-2 TLP).
// conv1: task = (y, 4-wide x chunk): 3x6 reg patch, 18 loads, 576 FMA/thread.
// ---------------------------------------------------------------------------
__global__ __launch_bounds__(512, 4)
void conv_pool_mfma(const float* __restrict__ xr, const float* __restrict__ xi,
                    const float* __restrict__ w1r, const float* __restrict__ b1r,
                    const float* __restrict__ w1i, const float* __restrict__ b1i,
                    const float* __restrict__ w2r, const float* __restrict__ b2r,
                    const float* __restrict__ w2i, const float* __restrict__ b2i,
                    float* __restrict__ pool_r, float* __restrict__ pool_m)
{
    __shared__ __align__(128) unsigned char s_x[SXBYTES];
    __shared__ float s_pool[C2];

    const int tid  = threadIdx.x;
    const int lane = tid & 63;
    const int img  = blockIdx.x;
    const int part = blockIdx.y;

    const float* xg = (part ? xi : xr) + img*(HH*WW);
    const float* w1 = part ? w1i : w1r;
    const float* b1 = part ? b1i : b1r;
    const float* w2 = part ? w2i : w2r;
    const float* b2 = part ? b2i : b2r;
    float* poolo = (part ? pool_m : pool_r) + img*C2;

    // zero whole LDS tile (borders stay zero = conv padding)
    for (int i = tid*16; i < SXBYTES; i += 512*16)
        *reinterpret_cast<int4*>(s_x + i) = make_int4(0,0,0,0);
    if (tid < C2) s_pool[tid] = 0.f;
    __syncthreads();

    // ---- conv1: task = (y, xc), 496 tasks. 3x6 patch in regs, 16ch x 4pos out.
    if (tid < HH*16) {
        const int y  = tid >> 4;
        const int x0 = (tid & 15) << 2;
        float patch[3][6];
        #pragma unroll
        for (int ky = 0; ky < 3; ++ky) {
            int row = y + ky - 1;
            #pragma unroll
            for (int j = 0; j < 6; ++j) {
                int col = x0 + j - 1;
                patch[ky][j] = (row >= 0 && row < HH && col >= 0 && col < WW)
                                 ? xg[row*WW + col] : 0.f;
            }
        }
        float acc[16][4];
        #pragma unroll
        for (int ch = 0; ch < 16; ++ch) {
            float bb = b1[ch];
            #pragma unroll
            for (int j = 0; j < 4; ++j) acc[ch][j] = bb;
        }
        #pragma unroll
        for (int ky = 0; ky < 3; ++ky)
            #pragma unroll
            for (int kx = 0; kx < 3; ++kx) {
                #pragma unroll
                for (int ch = 0; ch < 16; ++ch) {
                    float wv = w1[ch*9 + ky*3 + kx];     // uniform -> SGPR
                    #pragma unroll
                    for (int j = 0; j < 4; ++j)
                        acc[ch][j] += patch[ky][kx + j] * wv;
                }
            }
        #pragma unroll
        for (int j = 0; j < 4; ++j) {
            half8 lo, hi;
            #pragma unroll
            for (int ch = 0; ch < 8; ++ch) {
                lo[ch] = (_Float16)fmaxf(acc[ch][j],     0.f);
                hi[ch] = (_Float16)fmaxf(acc[8+ch][j],   0.f);
            }
            int pos = (y + 1)*XPAD + (x0 + j + 1);
            *reinterpret_cast<half8*>(s_x + swz(pos*32))      = lo;
            *reinterpret_cast<half8*>(s_x + swz(pos*32 + 16)) = hi;
        }
    }

    // ---- conv2 A-fragments + bias (after conv1 to limit live VGPRs) ----
    const int oc  = lane & 31;
    const int icb = (lane >> 5) * 8;
    half8 af[9];
    #pragma unroll
    for (int t = 0; t < 9; ++t) {
        half8 v;
        #pragma unroll
        for (int i = 0; i < 8; ++i)
            v[i] = (_Float16)w2[(oc*C1 + icb + i)*9 + t];
        af[t] = v;
    }
    float bias[16];
    #pragma unroll
    for (int r = 0; r < 16; ++r)
        bias[r] = b2[(r & 3) + 8*(r >> 2) + 4*(lane >> 5)];

    __syncthreads();

    // ---- conv2 + relu + pool: 62 N-tiles of 32 positions, striped by wave ----
    float pool[16];
    #pragma unroll
    for (int r = 0; r < 16; ++r) pool[r] = 0.f;

    const int wav = tid >> 6;
    const int halfoff = (lane >> 5) << 4;
    for (int tile = wav; tile < 62; tile += 8) {
        int y  = tile >> 1;
        int x0 = (tile & 1) * 32;
        floatx16 acc;
        #pragma unroll
        for (int r = 0; r < 16; ++r) acc[r] = bias[r];
        int pbase = y*XPAD + x0 + (lane & 31);      // pos at (ky,kx)=(0,0)
        #pragma unroll
        for (int ky = 0; ky < 3; ++ky) {
            #pragma unroll
            for (int kx = 0; kx < 3; ++kx) {
                int pos = pbase + ky*XPAD + kx;
                half8 b = *reinterpret_cast<const half8*>(s_x + swz(pos*32 + halfoff));
                acc = __builtin_amdgcn_mfma_f32_32x32x16_f16(af[ky*3+kx], b, acc, 0, 0, 0);
            }
        }
        #pragma unroll
        for (int r = 0; r < 16; ++r) pool[r] += fmaxf(acc[r], 0.f);
    }

    // reduce positions across the 32-lane half (butterfly), then across waves
    #pragma unroll
    for (int m = 1; m <= 16; m <<= 1) {
        #pragma unroll
        for (int r = 0; r < 16; ++r) pool[r] += __shfl_xor(pool[r], m, 64);
    }
    if ((lane & 31) == 0) {
        #pragma unroll
        for (int r = 0; r < 16; ++r)
            atomicAdd(&s_pool[(r & 3) + 8*(r >> 2) + 4*(lane >> 5)], pool[r]);
    }
    __syncthreads();
    if (tid < C2) poolo[tid] = s_pool[tid] * (1.f/1984.f);
}

// ---------------------------------------------------------------------------
// K2: feat = [r, m, sqrt(r^2+m^2), atan2(m,r)] ; fused = relu(feat @ fus_w.T + b)
// ---------------------------------------------------------------------------
__global__ __launch_bounds__(256)
void feat_fused_kernel(const float* __restrict__ pool_r, const float* __restrict__ pool_m,
                       const float* __restrict__ fus_w, const float* __restrict__ fus_b,
                       float* __restrict__ fused)
{
    __shared__ __align__(16) float s_feat[4][128];
    int tid = threadIdx.x;
    int n0 = blockIdx.x * 4;
    if (tid < 128) {
        int s = tid >> 5, c = tid & 31;
        float r = pool_r[(n0+s)*C2 + c];
        float m = pool_m[(n0+s)*C2 + c];
        s_feat[s][c]      = r;
        s_feat[s][32 + c] = m;
        s_feat[s][64 + c] = sqrtf(r*r + m*m);
        s_feat[s][96 + c] = atan2f(m, r);
    }
    __syncthreads();
    int s = tid >> 6, k = tid & 63;
    float acc = fus_b[k];
    const float4* wv = reinterpret_cast<const float4*>(fus_w + k*128);
    const float4* fv = reinterpret_cast<const float4*>(&s_feat[s][0]);
    #pragma unroll
    for (int j = 0; j < 32; ++j) {
        float4 w = wv[j], f = fv[j];
        acc += w.x*f.x + w.y*f.y + w.z*f.z + w.w*f.w;
    }
    fused[(n0+s)*64 + k] = fmaxf(acc, 0.f);
}

// ---------------------------------------------------------------------------
// K3: LSTMs. Blocks 0..15: forward 96-step scan, capture h at t==len-1.
// Blocks 16..31: backward LSTM = single step on fused[b, len-1] (zero state).
// __launch_bounds__(256,1): VGPR cap 512 so wih[64]+whh[64] stay in registers
// (no scratch spill). 4-way ILP accumulators; 2 barriers/step; cell state in
// a register.
// ---------------------------------------------------------------------------
__device__ __forceinline__ float sigm(float x){ return 1.f/(1.f + __expf(-x)); }
__device__ __forceinline__ float ftanh(float x){
    float xc = fminf(fmaxf(x, -15.f), 15.f);
    float e = __expf(2.f*xc);
    return (e - 1.f)/(e + 1.f);
}

__global__ __launch_bounds__(256, 1)
void lstm_kernel(const float* __restrict__ fused, const int* __restrict__ lengths,
                 const float* __restrict__ wf_ih, const float* __restrict__ wf_hh,
                 const float* __restrict__ bf_ih, const float* __restrict__ bf_hh,
                 const float* __restrict__ wb_ih, const float* __restrict__ wb_hh,
                 const float* __restrict__ bb_ih, const float* __restrict__ bb_hh,
                 float* __restrict__ last_f, float* __restrict__ hb0)
{
    __shared__ float s_x[64], s_h[64], s_g[256];
    const int g = threadIdx.x;           // gate row 0..255 (i|f|g|o blocks of 64)
    const int b = blockIdx.x & 15;
    const bool bwd = blockIdx.x >= 16;
    const int len = lengths[b];

    if (!bwd) {
        float wih[64], whh[64];
        const float* wi = wf_ih + g*64;
        const float* wh = wf_hh + g*64;
        #pragma unroll
        for (int j = 0; j < 64; j += 4) {
            float4 a = *reinterpret_cast<const float4*>(wi + j);
            wih[j]=a.x; wih[j+1]=a.y; wih[j+2]=a.z; wih[j+3]=a.w;
            float4 c = *reinterpret_cast<const float4*>(wh + j);
            whh[j]=c.x; whh[j+1]=c.y; whh[j+2]=c.z; whh[j+3]=c.w;
        }
        const float bg = bf_ih[g] + bf_hh[g];
        float creg = 0.f;
        if (g < 64) { s_h[g] = 0.f; s_x[g] = fused[(b*TT)*64 + g]; }
        __syncthreads();
        for (int t = 0; t < TT; ++t) {
            float a0=0.f, a1=0.f, a2=0.f, a3=0.f;
            #pragma unroll
            for (int j = 0; j < 64; j += 4) {
                a0 += s_x[j]  *wih[j];   a1 += s_x[j+1]*wih[j+1];
                a2 += s_x[j+2]*wih[j+2]; a3 += s_x[j+3]*wih[j+3];
            }
            #pragma unroll
            for (int j = 0; j < 64; j += 4) {
                a0 += s_h[j]  *whh[j];   a1 += s_h[j+1]*whh[j+1];
                a2 += s_h[j+2]*whh[j+2]; a3 += s_h[j+3]*whh[j+3];
            }
            s_g[g] = (a0+a1) + (a2+a3) + bg;
            __syncthreads();            // GEMV reads of s_x/s_h done; s_g ready
            if (g < 64) {
                float iv = sigm(s_g[g]);
                float fv = sigm(s_g[64+g]);
                float gv = ftanh(s_g[128+g]);
                float ov = sigm(s_g[192+g]);
                creg = fv*creg + iv*gv;
                float h = ov*ftanh(creg);
                s_h[g] = h;
                if (t == len-1) last_f[b*64+g] = h;
                if (t+1 < TT) s_x[g] = fused[(b*TT + t+1)*64 + g];
            }
            __syncthreads();            // s_x/s_h for t+1 visible
        }
    } else {
        float wih[64];
        const float* wi = wb_ih + g*64;
        #pragma unroll
        for (int j = 0; j < 64; j += 4) {
            float4 a = *reinterpret_cast<const float4*>(wi + j);
            wih[j]=a.x; wih[j+1]=a.y; wih[j+2]=a.z; wih[j+3]=a.w;
        }
        const float bg = bb_ih[g] + bb_hh[g];
        if (g < 64) s_x[g] = fused[(b*TT + (len-1))*64 + g];
        __syncthreads();
        float a0=0.f, a1=0.f, a2=0.f, a3=0.f;
        #pragma unroll
        for (int j = 0; j < 64; j += 4) {
            a0 += s_x[j]  *wih[j];   a1 += s_x[j+1]*wih[j+1];
            a2 += s_x[j+2]*wih[j+2]; a3 += s_x[j+3]*wih[j+3];
        }
        s_g[g] = (a0+a1) + (a2+a3) + bg;
        __syncthreads();
        if (g < 64) {
            float iv = sigm(s_g[g]);          // f gate irrelevant: c0 = 0
            float gv = ftanh(s_g[128+g]);
            float ov = sigm(s_g[192+g]);
            float c = iv*gv;
            float h = ov*ftanh(c);
            hb0[b*64+g] = h;
        }
    }
}

// ---------------------------------------------------------------------------
// K4: out[b,k] = fc_b[k] + last_f[b,:].fc_w[k,0:64] + hb0[b,:].fc_w[k,64:128]
// ---------------------------------------------------------------------------
__global__ __launch_bounds__(256)
void final_fc_kernel(const float* __restrict__ last_f, const float* __restrict__ hb0,
                     const float* __restrict__ fc_w, const float* __restrict__ fc_b,
                     float* __restrict__ out)
{
    int t = threadIdx.x;
    if (t >= BB*NC) return;
    int b = t / NC, k = t % NC;
    float acc = fc_b[k];
    const float* w = fc_w + k*128;
    #pragma unroll
    for (int j = 0; j < 64; ++j) acc += last_f[b*64+j]*w[j];
    #pragma unroll
    for (int j = 0; j < 64; ++j) acc += hb0[b*64+j]*w[64+j];
    out[b*NC + k] = acc;
}

extern "C" void kernel_launch(void* const* d_in, const int* in_sizes, int n_in,
                              void* d_out, int out_size, void* d_ws, size_t ws_size,
                              hipStream_t stream)
{
    const float* x_real = (const float*)d_in[0];
    const float* x_imag = (const float*)d_in[1];
    const int*   lengths= (const int*)d_in[2];
    const float* c1r_w = (const float*)d_in[3];
    const float* c1r_b = (const float*)d_in[4];
    const float* c1i_w = (const float*)d_in[5];
    const float* c1i_b = (const float*)d_in[6];
    const float* c2r_w = (const float*)d_in[7];
    const float* c2r_b = (const float*)d_in[8];
    const float* c2i_w = (const float*)d_in[9];
    const float* c2i_b = (const float*)d_in[10];
    const float* fus_w = (const float*)d_in[11];
    const float* fus_b = (const float*)d_in[12];
    const float* wf_ih = (const float*)d_in[13];
    const float* wf_hh = (const float*)d_in[14];
    const float* bf_ih = (const float*)d_in[15];
    const float* bf_hh = (const float*)d_in[16];
    const float* wb_ih = (const float*)d_in[17];
    const float* wb_hh = (const float*)d_in[18];
    const float* bb_ih = (const float*)d_in[19];
    const float* bb_hh = (const float*)d_in[20];
    const float* fc_w  = (const float*)d_in[21];
    const float* fc_b  = (const float*)d_in[22];
    float* out = (float*)d_out;

    // workspace layout (floats): pool_r | pool_m | fused | last_f | hb0
    float* ws     = (float*)d_ws;
    float* pool_r = ws;
    float* pool_m = pool_r + BT*C2;
    float* fusedb = pool_m + BT*C2;
    float* last_f = fusedb + BT*64;
    float* hb0    = last_f + BB*64;

    conv_pool_mfma<<<dim3(BT, 2), 512, 0, stream>>>(
        x_real, x_imag, c1r_w, c1r_b, c1i_w, c1i_b,
        c2r_w, c2r_b, c2i_w, c2i_b, pool_r, pool_m);

    feat_fused_kernel<<<BT/4, 256, 0, stream>>>(pool_r, pool_m, fus_w, fus_b, fusedb);

    lstm_kernel<<<32, 256, 0, stream>>>(fusedb, lengths,
        wf_ih, wf_hh, bf_ih, bf_hh, wb_ih, wb_hh, bb_ih, bb_hh, last_f, hb0);

    final_fc_kernel<<<1, 256, 0, stream>>>(last_f, hb0, fc_w, fc_b, out);
}

// Round 9
// 347.360 us; speedup vs baseline: 3.4815x; 1.0289x over previous
//
#include <hip/hip_runtime.h>
#include <math.h>

#define BB 16
#define TT 96
#define HH 31
#define WW 64
#define BT (BB*TT)
#define C1 16
#define C2 32
#define LH 64
#define NC 10

typedef _Float16 half8 __attribute__((ext_vector_type(8)));
typedef float floatx16 __attribute__((ext_vector_type(16)));

// padded conv1-output geometry: yp in [0,32] (y=-1..31), xp in [0,65] (x=-1..64)
#define XPAD 66
#define YPAD 33
#define NPOS (YPAD*XPAD)            // 2178 positions
#define SXBYTES (NPOS*32 + 128)     // 32B per position (16ch fp16) + swizzle pad

// XOR-swizzle: spread the 32B-stride position layout across LDS bank groups.
// Applied identically on write and read.
__device__ __forceinline__ int swz(int byte) {
    return byte ^ (((byte >> 7) & 7) << 4);
}

// ---------------------------------------------------------------------------
// K1: conv1(fp32) -> relu -> LDS fp16 channel-last -> conv2 as 9 tap-GEMMs on
// v_mfma_f32_32x32x16_f16 -> relu -> avgpool.
// 512 thr / 70KB LDS -> 2 blocks/CU -> 4 waves/SIMD.
// __launch_bounds__(512,2): VGPR cap 256 so af[9] (36 regs) stays RESIDENT
// (round-3's (512,4) cap made the compiler allocate 60 regs and re-load w2
// from global inside the tile loop - the latency bottleneck).
// conv1 runs as two 8-channel passes to cut its register peak (acc 64->32).
// Only the 194 border positions are zeroed (interior fully written by conv1).
// ---------------------------------------------------------------------------
__global__ __launch_bounds__(512, 2)
void conv_pool_mfma(const float* __restrict__ xr, const float* __restrict__ xi,
                    const float* __restrict__ w1r, const float* __restrict__ b1r,
                    const float* __restrict__ w1i, const float* __restrict__ b1i,
                    const float* __restrict__ w2r, const float* __restrict__ b2r,
                    const float* __restrict__ w2i, const float* __restrict__ b2i,
                    float* __restrict__ pool_r, float* __restrict__ pool_m)
{
    __shared__ __align__(128) unsigned char s_x[SXBYTES];
    __shared__ float s_pool[C2];

    const int tid  = threadIdx.x;
    const int lane = tid & 63;
    const int img  = blockIdx.x;
    const int part = blockIdx.y;

    const float* xg = (part ? xi : xr) + img*(HH*WW);
    const float* w1 = part ? w1i : w1r;
    const float* b1 = part ? b1i : b1r;
    const float* w2 = part ? w2i : w2r;
    const float* b2 = part ? b2i : b2r;
    float* poolo = (part ? pool_m : pool_r) + img*C2;

    if (tid < C2) s_pool[tid] = 0.f;

    // zero the 194 border positions (yp=0, yp=32 rows; xp=0,65 cols)
    if (tid < 194) {
        int pos;
        if (tid < 66)       pos = tid;                    // yp = 0
        else if (tid < 132) pos = 32*XPAD + (tid - 66);   // yp = 32
        else {
            int i = tid - 132;
            pos = (1 + (i >> 1))*XPAD + ((i & 1) ? 65 : 0);
        }
        *reinterpret_cast<int4*>(s_x + swz(pos*32))      = make_int4(0,0,0,0);
        *reinterpret_cast<int4*>(s_x + swz(pos*32 + 16)) = make_int4(0,0,0,0);
    }

    // ---- conv1: task = (y, xc), 496 tasks; 3x6 patch in regs; 2 passes of 8ch.
    if (tid < HH*16) {
        const int y  = tid >> 4;
        const int x0 = (tid & 15) << 2;
        float patch[3][6];
        #pragma unroll
        for (int ky = 0; ky < 3; ++ky) {
            int row = y + ky - 1;
            #pragma unroll
            for (int j = 0; j < 6; ++j) {
                int col = x0 + j - 1;
                patch[ky][j] = (row >= 0 && row < HH && col >= 0 && col < WW)
                                 ? xg[row*WW + col] : 0.f;
            }
        }
        #pragma unroll
        for (int p = 0; p < 2; ++p) {
            float acc[8][4];
            #pragma unroll
            for (int ch = 0; ch < 8; ++ch) {
                float bb = b1[p*8 + ch];
                #pragma unroll
                for (int j = 0; j < 4; ++j) acc[ch][j] = bb;
            }
            #pragma unroll
            for (int ky = 0; ky < 3; ++ky)
                #pragma unroll
                for (int kx = 0; kx < 3; ++kx) {
                    #pragma unroll
                    for (int ch = 0; ch < 8; ++ch) {
                        float wv = w1[(p*8 + ch)*9 + ky*3 + kx];   // uniform -> SGPR
                        #pragma unroll
                        for (int j = 0; j < 4; ++j)
                            acc[ch][j] += patch[ky][kx + j] * wv;
                    }
                }
            #pragma unroll
            for (int j = 0; j < 4; ++j) {
                half8 v;
                #pragma unroll
                for (int ch = 0; ch < 8; ++ch)
                    v[ch] = (_Float16)fmaxf(acc[ch][j], 0.f);
                int pos = (y + 1)*XPAD + (x0 + j + 1);
                *reinterpret_cast<half8*>(s_x + swz(pos*32 + p*16)) = v;
            }
        }
    }

    // ---- conv2 A-fragments + bias (must stay register-resident) ----
    const int oc  = lane & 31;
    const int icb = (lane >> 5) * 8;
    half8 af[9];
    #pragma unroll
    for (int t = 0; t < 9; ++t) {
        half8 v;
        #pragma unroll
        for (int i = 0; i < 8; ++i)
            v[i] = (_Float16)w2[(oc*C1 + icb + i)*9 + t];
        af[t] = v;
    }
    float bias[16];
    #pragma unroll
    for (int r = 0; r < 16; ++r)
        bias[r] = b2[(r & 3) + 8*(r >> 2) + 4*(lane >> 5)];

    __syncthreads();

    // ---- conv2 + relu + pool: 62 N-tiles of 32 positions, striped by wave.
    // B-fragment loads lead the MFMAs by one ky-row (explicit names).
    float pool[16];
    #pragma unroll
    for (int r = 0; r < 16; ++r) pool[r] = 0.f;

    const int wav = tid >> 6;
    const int halfoff = (lane >> 5) << 4;

    #define LDB(dst, ky, kx) do { \
        int byte_ = (pbase + (ky)*XPAD + (kx))*32 + halfoff; \
        dst = *reinterpret_cast<const half8*>(s_x + swz(byte_)); } while (0)

    for (int tile = wav; tile < 62; tile += 8) {
        int y  = tile >> 1;
        int x0 = (tile & 1) * 32;
        int pbase = y*XPAD + x0 + (lane & 31);
        floatx16 acc;
        #pragma unroll
        for (int r = 0; r < 16; ++r) acc[r] = bias[r];

        half8 r0a, r0b, r0c, r1a, r1b, r1c, r2a, r2b, r2c;
        LDB(r0a, 0, 0); LDB(r0b, 0, 1); LDB(r0c, 0, 2);
        LDB(r1a, 1, 0); LDB(r1b, 1, 1); LDB(r1c, 1, 2);
        acc = __builtin_amdgcn_mfma_f32_32x32x16_f16(af[0], r0a, acc, 0, 0, 0);
        acc = __builtin_amdgcn_mfma_f32_32x32x16_f16(af[1], r0b, acc, 0, 0, 0);
        acc = __builtin_amdgcn_mfma_f32_32x32x16_f16(af[2], r0c, acc, 0, 0, 0);
        LDB(r2a, 2, 0); LDB(r2b, 2, 1); LDB(r2c, 2, 2);
        acc = __builtin_amdgcn_mfma_f32_32x32x16_f16(af[3], r1a, acc, 0, 0, 0);
        acc = __builtin_amdgcn_mfma_f32_32x32x16_f16(af[4], r1b, acc, 0, 0, 0);
        acc = __builtin_amdgcn_mfma_f32_32x32x16_f16(af[5], r1c, acc, 0, 0, 0);
        acc = __builtin_amdgcn_mfma_f32_32x32x16_f16(af[6], r2a, acc, 0, 0, 0);
        acc = __builtin_amdgcn_mfma_f32_32x32x16_f16(af[7], r2b, acc, 0, 0, 0);
        acc = __builtin_amdgcn_mfma_f32_32x32x16_f16(af[8], r2c, acc, 0, 0, 0);

        #pragma unroll
        for (int r = 0; r < 16; ++r) pool[r] += fmaxf(acc[r], 0.f);
    }
    #undef LDB

    // reduce positions across the 32-lane half (butterfly), then across waves
    #pragma unroll
    for (int m = 1; m <= 16; m <<= 1) {
        #pragma unroll
        for (int r = 0; r < 16; ++r) pool[r] += __shfl_xor(pool[r], m, 64);
    }
    if ((lane & 31) == 0) {
        #pragma unroll
        for (int r = 0; r < 16; ++r)
            atomicAdd(&s_pool[(r & 3) + 8*(r >> 2) + 4*(lane >> 5)], pool[r]);
    }
    __syncthreads();
    if (tid < C2) poolo[tid] = s_pool[tid] * (1.f/1984.f);
}

// ---------------------------------------------------------------------------
// K2: fused feat+FC+LSTM. One block per (sample, direction).
// Blocks 0..15 (fwd):  F1 feat[96][128] -> F2 fused[96][64] -> F3 input-gate
// precompute gates_x[96][256] (overwrites feat region) -> F4 96-step scan
// touching only LDS (64-FMA h-GEMV per step).
// Blocks 16..31 (bwd): single step on fused[b,len-1] from zero state.
// LDS: 98304 (gates/feat union) + 24576 (fused) + h + g  = ~124 KB.
// ---------------------------------------------------------------------------
__device__ __forceinline__ float sigm(float x){ return 1.f/(1.f + __expf(-x)); }
__device__ __forceinline__ float ftanh(float x){
    float xc = fminf(fmaxf(x, -15.f), 15.f);
    float e = __expf(2.f*xc);
    return (e - 1.f)/(e + 1.f);
}

__global__ __launch_bounds__(512, 1)
void lstm_fused(const float* __restrict__ pool_r, const float* __restrict__ pool_m,
                const int* __restrict__ lengths,
                const float* __restrict__ fus_w, const float* __restrict__ fus_b,
                const float* __restrict__ wf_ih, const float* __restrict__ wf_hh,
                const float* __restrict__ bf_ih, const float* __restrict__ bf_hh,
                const float* __restrict__ wb_ih, const float* __restrict__ wb_hh,
                const float* __restrict__ bb_ih, const float* __restrict__ bb_hh,
                float* __restrict__ last_f, float* __restrict__ hb0)
{
    __shared__ __align__(16) float s_gx[TT*256];     // gates_x; first 49KB = feat
    __shared__ __align__(16) float s_fused[TT][64];
    __shared__ float s_h[64];
    __shared__ float s_g[256];

    const int tid = threadIdx.x;
    const int b   = blockIdx.x & 15;
    const bool bwd = blockIdx.x >= 16;
    const int len = lengths[b];

    if (!bwd) {
        // ---- F1: feat[t][128] into s_gx ----
        for (int i = tid; i < TT*32; i += 512) {
            int t = i >> 5, c = i & 31;
            float r = pool_r[(b*TT + t)*C2 + c];
            float m = pool_m[(b*TT + t)*C2 + c];
            float* f = s_gx + t*128;
            f[c]      = r;
            f[32 + c] = m;
            f[64 + c] = sqrtf(r*r + m*m);
            f[96 + c] = atan2f(m, r);
        }
        __syncthreads();

        // ---- F2: fused[t][k] = relu(feat[t] . fus_w[k] + fus_b[k]) ----
        {
            const int k = tid & 63, tq = tid >> 6;    // 8 groups x 12 t
            float4 wreg[32];
            #pragma unroll
            for (int q = 0; q < 32; ++q)
                wreg[q] = *reinterpret_cast<const float4*>(fus_w + k*128 + q*4);
            const float bk = fus_b[k];
            for (int j = 0; j < 12; ++j) {
                int t = tq*12 + j;
                const float* f = s_gx + t*128;
                float a0=0.f, a1=0.f, a2=0.f, a3=0.f;
                #pragma unroll
                for (int q = 0; q < 32; ++q) {
                    float4 fv = *reinterpret_cast<const float4*>(f + q*4);
                    a0 += wreg[q].x*fv.x; a1 += wreg[q].y*fv.y;
                    a2 += wreg[q].z*fv.z; a3 += wreg[q].w*fv.w;
                }
                s_fused[t][k] = fmaxf((a0+a1) + (a2+a3) + bk, 0.f);
            }
        }
        __syncthreads();

        // ---- F3: gates_x[t][g] = fused[t] . wf_ih[g] + (bf_ih+bf_hh)[g] ----
        {
            const int g = tid & 255, th = tid >> 8;   // 2 t-halves
            float wih[64];
            #pragma unroll
            for (int q = 0; q < 64; q += 4) {
                float4 a = *reinterpret_cast<const float4*>(wf_ih + g*64 + q);
                wih[q]=a.x; wih[q+1]=a.y; wih[q+2]=a.z; wih[q+3]=a.w;
            }
            const float bg = bf_ih[g] + bf_hh[g];
            for (int j = 0; j < 48; ++j) {
                int t = th*48 + j;
                float a0=0.f, a1=0.f, a2=0.f, a3=0.f;
                #pragma unroll
                for (int q = 0; q < 64; q += 4) {
                    float4 fv = *reinterpret_cast<const float4*>(&s_fused[t][q]);
                    a0 += wih[q]*fv.x;   a1 += wih[q+1]*fv.y;
                    a2 += wih[q+2]*fv.z; a3 += wih[q+3]*fv.w;
                }
                s_gx[t*256 + g] = (a0+a1) + (a2+a3) + bg;
            }
        }
        __syncthreads();

        // ---- F4: scan ----
        const int g = tid & 255;
        float whh[64];
        #pragma unroll
        for (int q = 0; q < 64; q += 4) {
            float4 a = *reinterpret_cast<const float4*>(wf_hh + g*64 + q);
            whh[q]=a.x; whh[q+1]=a.y; whh[q+2]=a.z; whh[q+3]=a.w;
        }
        if (tid < 64) s_h[tid] = 0.f;
        __syncthreads();
        float creg = 0.f;
        for (int t = 0; t < TT; ++t) {
            if (tid < 256) {
                float a0=0.f, a1=0.f, a2=0.f, a3=0.f;
                #pragma unroll
                for (int q = 0; q < 64; q += 4) {
                    float4 hv = *reinterpret_cast<const float4*>(&s_h[q]);
                    a0 += whh[q]*hv.x;   a1 += whh[q+1]*hv.y;
                    a2 += whh[q+2]*hv.z; a3 += whh[q+3]*hv.w;
                }
                s_g[g] = (a0+a1) + (a2+a3) + s_gx[t*256 + g];
            }
            __syncthreads();
            if (tid < 64) {
                float iv = sigm(s_g[tid]);
                float fv = sigm(s_g[64+tid]);
                float gv = ftanh(s_g[128+tid]);
                float ov = sigm(s_g[192+tid]);
                creg = fv*creg + iv*gv;
                float h = ov*ftanh(creg);
                s_h[tid] = h;
                if (t == len-1) last_f[b*64+tid] = h;
            }
            __syncthreads();
        }
    } else {
        // ---- backward LSTM = one step on fused[b, len-1] from zero state ----
        const int t0 = len - 1;
        if (tid < 32) {
            int c = tid;
            float r = pool_r[(b*TT + t0)*C2 + c];
            float m = pool_m[(b*TT + t0)*C2 + c];
            s_gx[c]      = r;
            s_gx[32 + c] = m;
            s_gx[64 + c] = sqrtf(r*r + m*m);
            s_gx[96 + c] = atan2f(m, r);
        }
        __syncthreads();
        if (tid < 64) {
            float acc = fus_b[tid];
            const float4* wv = reinterpret_cast<const float4*>(fus_w + tid*128);
            #pragma unroll
            for (int q = 0; q < 32; ++q) {
                float4 w = wv[q];
                float4 f = *reinterpret_cast<const float4*>(s_gx + q*4);
                acc += w.x*f.x + w.y*f.y + w.z*f.z + w.w*f.w;
            }
            s_fused[0][tid] = fmaxf(acc, 0.f);
        }
        __syncthreads();
        if (tid < 256) {
            float acc = bb_ih[tid] + bb_hh[tid];
            const float4* wv = reinterpret_cast<const float4*>(wb_ih + tid*64);
            #pragma unroll
            for (int q = 0; q < 16; ++q) {
                float4 w = wv[q];
                float4 f = *reinterpret_cast<const float4*>(&s_fused[0][q*4]);
                acc += w.x*f.x + w.y*f.y + w.z*f.z + w.w*f.w;
            }
            s_g[tid] = acc;
        }
        __syncthreads();
        if (tid < 64) {
            float iv = sigm(s_g[tid]);            // f gate irrelevant: c0 = 0
            float gv = ftanh(s_g[128+tid]);
            float ov = sigm(s_g[192+tid]);
            float c = iv*gv;
            hb0[b*64+tid] = ov*ftanh(c);
        }
    }
}

// ---------------------------------------------------------------------------
// K3: out[b,k] = fc_b[k] + last_f[b,:].fc_w[k,0:64] + hb0[b,:].fc_w[k,64:128]
// ---------------------------------------------------------------------------
__global__ __launch_bounds__(256)
void final_fc_kernel(const float* __restrict__ last_f, const float* __restrict__ hb0,
                     const float* __restrict__ fc_w, const float* __restrict__ fc_b,
                     float* __restrict__ out)
{
    int t = threadIdx.x;
    if (t >= BB*NC) return;
    int b = t / NC, k = t % NC;
    float acc = fc_b[k];
    const float* w = fc_w + k*128;
    #pragma unroll
    for (int j = 0; j < 64; ++j) acc += last_f[b*64+j]*w[j];
    #pragma unroll
    for (int j = 0; j < 64; ++j) acc += hb0[b*64+j]*w[64+j];
    out[b*NC + k] = acc;
}

extern "C" void kernel_launch(void* const* d_in, const int* in_sizes, int n_in,
                              void* d_out, int out_size, void* d_ws, size_t ws_size,
                              hipStream_t stream)
{
    const float* x_real = (const float*)d_in[0];
    const float* x_imag = (const float*)d_in[1];
    const int*   lengths= (const int*)d_in[2];
    const float* c1r_w = (const float*)d_in[3];
    const float* c1r_b = (const float*)d_in[4];
    const float* c1i_w = (const float*)d_in[5];
    const float* c1i_b = (const float*)d_in[6];
    const float* c2r_w = (const float*)d_in[7];
    const float* c2r_b = (const float*)d_in[8];
    const float* c2i_w = (const float*)d_in[9];
    const float* c2i_b = (const float*)d_in[10];
    const float* fus_w = (const float*)d_in[11];
    const float* fus_b = (const float*)d_in[12];
    const float* wf_ih = (const float*)d_in[13];
    const float* wf_hh = (const float*)d_in[14];
    const float* bf_ih = (const float*)d_in[15];
    const float* bf_hh = (const float*)d_in[16];
    const float* wb_ih = (const float*)d_in[17];
    const float* wb_hh = (const float*)d_in[18];
    const float* bb_ih = (const float*)d_in[19];
    const float* bb_hh = (const float*)d_in[20];
    const float* fc_w  = (const float*)d_in[21];
    const float* fc_b  = (const float*)d_in[22];
    float* out = (float*)d_out;

    // workspace layout (floats): pool_r | pool_m | last_f | hb0
    float* ws     = (float*)d_ws;
    float* pool_r = ws;
    float* pool_m = pool_r + BT*C2;
    float* last_f = pool_m + BT*C2;
    float* hb0    = last_f + BB*LH;

    conv_pool_mfma<<<dim3(BT, 2), 512, 0, stream>>>(
        x_real, x_imag, c1r_w, c1r_b, c1i_w, c1i_b,
        c2r_w, c2r_b, c2i_w, c2i_b, pool_r, pool_m);

    lstm_fused<<<32, 512, 0, stream>>>(pool_r, pool_m, lengths,
        fus_w, fus_b, wf_ih, wf_hh, bf_ih, bf_hh,
        wb_ih, wb_hh, bb_ih, bb_hh, last_f, hb0);

    final_fc_kernel<<<1, 256, 0, stream>>>(last_f, hb0, fc_w, fc_b, out);
}

// Round 10
// 299.347 us; speedup vs baseline: 4.0399x; 1.1604x over previous
//
#include <hip/hip_runtime.h>
#include <math.h>

#define BB 16
#define TT 96
#define HH 31
#define WW 64
#define BT (BB*TT)
#define C1 16
#define C2 32
#define LH 64
#define NC 10

typedef _Float16 half8 __attribute__((ext_vector_type(8)));
typedef float floatx16 __attribute__((ext_vector_type(16)));

// padded conv1-output geometry: yp in [0,32] (y=-1..31), xp in [0,65] (x=-1..64)
#define XPAD 66
#define YPAD 33
#define NPOS (YPAD*XPAD)            // 2178 positions
#define SXBYTES (NPOS*32 + 128)     // 32B per position (16ch fp16) + swizzle pad

// XOR-swizzle: spread the 32B-stride position layout across LDS bank groups.
// Applied identically on write and read.
__device__ __forceinline__ int swz(int byte) {
    return byte ^ (((byte >> 7) & 7) << 4);
}

// ---------------------------------------------------------------------------
// K1: conv1(fp32) -> relu -> LDS fp16 channel-last -> conv2 as 9 tap-GEMMs on
// v_mfma_f32_32x32x16_f16 -> relu -> avgpool.  (unchanged from round 3/9)
// ---------------------------------------------------------------------------
__global__ __launch_bounds__(512, 2)
void conv_pool_mfma(const float* __restrict__ xr, const float* __restrict__ xi,
                    const float* __restrict__ w1r, const float* __restrict__ b1r,
                    const float* __restrict__ w1i, const float* __restrict__ b1i,
                    const float* __restrict__ w2r, const float* __restrict__ b2r,
                    const float* __restrict__ w2i, const float* __restrict__ b2i,
                    float* __restrict__ pool_r, float* __restrict__ pool_m)
{
    __shared__ __align__(128) unsigned char s_x[SXBYTES];
    __shared__ float s_pool[C2];

    const int tid  = threadIdx.x;
    const int lane = tid & 63;
    const int img  = blockIdx.x;
    const int part = blockIdx.y;

    const float* xg = (part ? xi : xr) + img*(HH*WW);
    const float* w1 = part ? w1i : w1r;
    const float* b1 = part ? b1i : b1r;
    const float* w2 = part ? w2i : w2r;
    const float* b2 = part ? b2i : b2r;
    float* poolo = (part ? pool_m : pool_r) + img*C2;

    if (tid < C2) s_pool[tid] = 0.f;

    // zero the 194 border positions (yp=0, yp=32 rows; xp=0,65 cols)
    if (tid < 194) {
        int pos;
        if (tid < 66)       pos = tid;                    // yp = 0
        else if (tid < 132) pos = 32*XPAD + (tid - 66);   // yp = 32
        else {
            int i = tid - 132;
            pos = (1 + (i >> 1))*XPAD + ((i & 1) ? 65 : 0);
        }
        *reinterpret_cast<int4*>(s_x + swz(pos*32))      = make_int4(0,0,0,0);
        *reinterpret_cast<int4*>(s_x + swz(pos*32 + 16)) = make_int4(0,0,0,0);
    }

    // ---- conv1: task = (y, xc), 496 tasks; 3x6 patch in regs; 2 passes of 8ch.
    if (tid < HH*16) {
        const int y  = tid >> 4;
        const int x0 = (tid & 15) << 2;
        float patch[3][6];
        #pragma unroll
        for (int ky = 0; ky < 3; ++ky) {
            int row = y + ky - 1;
            #pragma unroll
            for (int j = 0; j < 6; ++j) {
                int col = x0 + j - 1;
                patch[ky][j] = (row >= 0 && row < HH && col >= 0 && col < WW)
                                 ? xg[row*WW + col] : 0.f;
            }
        }
        #pragma unroll
        for (int p = 0; p < 2; ++p) {
            float acc[8][4];
            #pragma unroll
            for (int ch = 0; ch < 8; ++ch) {
                float bb = b1[p*8 + ch];
                #pragma unroll
                for (int j = 0; j < 4; ++j) acc[ch][j] = bb;
            }
            #pragma unroll
            for (int ky = 0; ky < 3; ++ky)
                #pragma unroll
                for (int kx = 0; kx < 3; ++kx) {
                    #pragma unroll
                    for (int ch = 0; ch < 8; ++ch) {
                        float wv = w1[(p*8 + ch)*9 + ky*3 + kx];   // uniform -> SGPR
                        #pragma unroll
                        for (int j = 0; j < 4; ++j)
                            acc[ch][j] += patch[ky][kx + j] * wv;
                    }
                }
            #pragma unroll
            for (int j = 0; j < 4; ++j) {
                half8 v;
                #pragma unroll
                for (int ch = 0; ch < 8; ++ch)
                    v[ch] = (_Float16)fmaxf(acc[ch][j], 0.f);
                int pos = (y + 1)*XPAD + (x0 + j + 1);
                *reinterpret_cast<half8*>(s_x + swz(pos*32 + p*16)) = v;
            }
        }
    }

    // ---- conv2 A-fragments + bias (must stay register-resident) ----
    const int oc  = lane & 31;
    const int icb = (lane >> 5) * 8;
    half8 af[9];
    #pragma unroll
    for (int t = 0; t < 9; ++t) {
        half8 v;
        #pragma unroll
        for (int i = 0; i < 8; ++i)
            v[i] = (_Float16)w2[(oc*C1 + icb + i)*9 + t];
        af[t] = v;
    }
    float bias[16];
    #pragma unroll
    for (int r = 0; r < 16; ++r)
        bias[r] = b2[(r & 3) + 8*(r >> 2) + 4*(lane >> 5)];

    __syncthreads();

    // ---- conv2 + relu + pool: 62 N-tiles of 32 positions, striped by wave.
    float pool[16];
    #pragma unroll
    for (int r = 0; r < 16; ++r) pool[r] = 0.f;

    const int wav = tid >> 6;
    const int halfoff = (lane >> 5) << 4;

    #define LDB(dst, ky, kx) do { \
        int byte_ = (pbase + (ky)*XPAD + (kx))*32 + halfoff; \
        dst = *reinterpret_cast<const half8*>(s_x + swz(byte_)); } while (0)

    for (int tile = wav; tile < 62; tile += 8) {
        int y  = tile >> 1;
        int x0 = (tile & 1) * 32;
        int pbase = y*XPAD + x0 + (lane & 31);
        floatx16 acc;
        #pragma unroll
        for (int r = 0; r < 16; ++r) acc[r] = bias[r];

        half8 r0a, r0b, r0c, r1a, r1b, r1c, r2a, r2b, r2c;
        LDB(r0a, 0, 0); LDB(r0b, 0, 1); LDB(r0c, 0, 2);
        LDB(r1a, 1, 0); LDB(r1b, 1, 1); LDB(r1c, 1, 2);
        acc = __builtin_amdgcn_mfma_f32_32x32x16_f16(af[0], r0a, acc, 0, 0, 0);
        acc = __builtin_amdgcn_mfma_f32_32x32x16_f16(af[1], r0b, acc, 0, 0, 0);
        acc = __builtin_amdgcn_mfma_f32_32x32x16_f16(af[2], r0c, acc, 0, 0, 0);
        LDB(r2a, 2, 0); LDB(r2b, 2, 1); LDB(r2c, 2, 2);
        acc = __builtin_amdgcn_mfma_f32_32x32x16_f16(af[3], r1a, acc, 0, 0, 0);
        acc = __builtin_amdgcn_mfma_f32_32x32x16_f16(af[4], r1b, acc, 0, 0, 0);
        acc = __builtin_amdgcn_mfma_f32_32x32x16_f16(af[5], r1c, acc, 0, 0, 0);
        acc = __builtin_amdgcn_mfma_f32_32x32x16_f16(af[6], r2a, acc, 0, 0, 0);
        acc = __builtin_amdgcn_mfma_f32_32x32x16_f16(af[7], r2b, acc, 0, 0, 0);
        acc = __builtin_amdgcn_mfma_f32_32x32x16_f16(af[8], r2c, acc, 0, 0, 0);

        #pragma unroll
        for (int r = 0; r < 16; ++r) pool[r] += fmaxf(acc[r], 0.f);
    }
    #undef LDB

    #pragma unroll
    for (int m = 1; m <= 16; m <<= 1) {
        #pragma unroll
        for (int r = 0; r < 16; ++r) pool[r] += __shfl_xor(pool[r], m, 64);
    }
    if ((lane & 31) == 0) {
        #pragma unroll
        for (int r = 0; r < 16; ++r)
            atomicAdd(&s_pool[(r & 3) + 8*(r >> 2) + 4*(lane >> 5)], pool[r]);
    }
    __syncthreads();
    if (tid < C2) poolo[tid] = s_pool[tid] * (1.f/1984.f);
}

// ---------------------------------------------------------------------------
// K2a: prep — one block per (b,t). feat[128] -> fused[64] -> gates_x[256].
// 1536 blocks = full-GPU parallel. Weights stream from L2 (~130 MB total @
// 34 TB/s ~ 4 us). Also writes fused[1536][64] (bwd path needs fused[len-1]).
// ---------------------------------------------------------------------------
__device__ __forceinline__ float sigm(float x){ return 1.f/(1.f + __expf(-x)); }
__device__ __forceinline__ float ftanh(float x){
    float xc = fminf(fmaxf(x, -15.f), 15.f);
    float e = __expf(2.f*xc);
    return (e - 1.f)/(e + 1.f);
}

__global__ __launch_bounds__(256)
void lstm_prep(const float* __restrict__ pool_r, const float* __restrict__ pool_m,
               const float* __restrict__ fus_w, const float* __restrict__ fus_b,
               const float* __restrict__ wf_ih,
               const float* __restrict__ bf_ih, const float* __restrict__ bf_hh,
               float* __restrict__ fusedg, float* __restrict__ gates_x)
{
    __shared__ __align__(16) float s_feat[128];
    __shared__ __align__(16) float s_fused[64];
    const int bt  = blockIdx.x;          // b*96 + t
    const int tid = threadIdx.x;

    if (tid < 32) {
        float r = pool_r[bt*C2 + tid];
        float m = pool_m[bt*C2 + tid];
        s_feat[tid]      = r;
        s_feat[32 + tid] = m;
        s_feat[64 + tid] = sqrtf(r*r + m*m);
        s_feat[96 + tid] = atan2f(m, r);
    }
    __syncthreads();

    if (tid < 64) {
        float acc = fus_b[tid];
        const float4* wv = reinterpret_cast<const float4*>(fus_w + tid*128);
        float a0=0.f, a1=0.f, a2=0.f, a3=0.f;
        #pragma unroll
        for (int q = 0; q < 32; ++q) {
            float4 w = wv[q];
            float4 f = *reinterpret_cast<const float4*>(s_feat + q*4);
            a0 += w.x*f.x; a1 += w.y*f.y; a2 += w.z*f.z; a3 += w.w*f.w;
        }
        float v = fmaxf(acc + (a0+a1) + (a2+a3), 0.f);
        s_fused[tid] = v;
        fusedg[bt*64 + tid] = v;
    }
    __syncthreads();

    {
        float acc = bf_ih[tid] + bf_hh[tid];
        const float4* wv = reinterpret_cast<const float4*>(wf_ih + tid*64);
        float a0=0.f, a1=0.f, a2=0.f, a3=0.f;
        #pragma unroll
        for (int q = 0; q < 16; ++q) {
            float4 w = wv[q];
            float4 f = *reinterpret_cast<const float4*>(s_fused + q*4);
            a0 += w.x*f.x; a1 += w.y*f.y; a2 += w.z*f.z; a3 += w.w*f.w;
        }
        gates_x[bt*256 + tid] = acc + (a0+a1) + (a2+a3);
    }
}

// ---------------------------------------------------------------------------
// K2b: scan. Blocks 0..15: forward 96-step recurrence, ONE barrier per step.
// Gate->lane map: wave w, lane ln; unit u = w*16+(ln&15), gate q = ln>>4.
// All 4 gates of unit u live in the same wave -> after the 64-FMA h-GEMV,
// 3x shfl_xor(16/32/32) assembles i,f,g,o per lane; h/c update is in-wave
// (replicated x4). s_h double-buffered (read t&1, write (t+1)&1) so a single
// __syncthreads per step suffices (no read/write race). gates_x[t+1]
// prefetched from global one full step ahead.
// Blocks 16..31: backward LSTM = one step on fused[b,len-1] from zero state.
// ---------------------------------------------------------------------------
__global__ __launch_bounds__(256, 1)
void lstm_scan(const float* __restrict__ gates_x, const float* __restrict__ fusedg,
               const int* __restrict__ lengths,
               const float* __restrict__ wf_hh,
               const float* __restrict__ wb_ih,
               const float* __restrict__ bb_ih, const float* __restrict__ bb_hh,
               float* __restrict__ last_f, float* __restrict__ hb0)
{
    const int tid = threadIdx.x;
    const int b   = blockIdx.x & 15;
    const int len = lengths[b];

    if (blockIdx.x < 16) {
        __shared__ __align__(16) float s_h[2][64];
        const int ln = tid & 63;
        const int w  = tid >> 6;
        const int q  = ln >> 4;            // gate: 0=i 1=f 2=g 3=o
        const int u  = w*16 + (ln & 15);   // hidden unit
        const int g  = q*64 + u;           // gate row

        float whh[64];
        #pragma unroll
        for (int j = 0; j < 64; j += 4) {
            float4 a = *reinterpret_cast<const float4*>(wf_hh + g*64 + j);
            whh[j]=a.x; whh[j+1]=a.y; whh[j+2]=a.z; whh[j+3]=a.w;
        }
        if (q == 0) s_h[0][u] = 0.f;
        __syncthreads();

        const float* gxp = gates_x + (b*TT)*256 + g;
        float gx = gxp[0];
        float creg = 0.f;
        for (int t = 0; t < TT; ++t) {
            // prefetch next step's input-gate preactivation (hide HBM/L2 lat.)
            float gxn = (t+1 < TT) ? gxp[(t+1)*256] : 0.f;

            const int cur = t & 1;
            float a0=0.f, a1=0.f, a2=0.f, a3=0.f;
            #pragma unroll
            for (int j = 0; j < 64; j += 4) {
                float4 hv = *reinterpret_cast<const float4*>(&s_h[cur][j]);
                a0 += whh[j]*hv.x;   a1 += whh[j+1]*hv.y;
                a2 += whh[j+2]*hv.z; a3 += whh[j+3]*hv.w;
            }
            float acc = gx + (a0+a1) + (a2+a3);

            // assemble all 4 gate values per lane (sources verified per-q)
            float p1 = __shfl_xor(acc, 16, 64);   // gate q^1
            float p2 = __shfl_xor(acc, 32, 64);   // gate q^2
            float p3 = __shfl_xor(p1,  32, 64);   // gate q^3
            float g0 = (q==0)?acc : (q==1)?p1 : (q==2)?p2 : p3;
            float g1 = (q==1)?acc : (q==0)?p1 : (q==3)?p2 : p3;
            float g2 = (q==2)?acc : (q==3)?p1 : (q==0)?p2 : p3;
            float g3 = (q==3)?acc : (q==2)?p1 : (q==1)?p2 : p3;

            creg = sigm(g1)*creg + sigm(g0)*ftanh(g2);
            float h = sigm(g3)*ftanh(creg);

            if (q == 0) {
                s_h[cur^1][u] = h;
                if (t == len-1) last_f[b*64 + u] = h;
            }
            gx = gxn;
            __syncthreads();
        }
    } else {
        __shared__ __align__(16) float s_f[64];
        __shared__ float s_g[256];
        if (tid < 64) s_f[tid] = fusedg[(b*TT + (len-1))*64 + tid];
        __syncthreads();
        {
            float acc = bb_ih[tid] + bb_hh[tid];
            const float4* wv = reinterpret_cast<const float4*>(wb_ih + tid*64);
            float a0=0.f, a1=0.f, a2=0.f, a3=0.f;
            #pragma unroll
            for (int qq = 0; qq < 16; ++qq) {
                float4 wvv = wv[qq];
                float4 f = *reinterpret_cast<const float4*>(s_f + qq*4);
                a0 += wvv.x*f.x; a1 += wvv.y*f.y; a2 += wvv.z*f.z; a3 += wvv.w*f.w;
            }
            s_g[tid] = acc + (a0+a1) + (a2+a3);
        }
        __syncthreads();
        if (tid < 64) {
            float iv = sigm(s_g[tid]);            // f gate irrelevant: c0 = 0
            float gv = ftanh(s_g[128+tid]);
            float ov = sigm(s_g[192+tid]);
            hb0[b*64 + tid] = ov*ftanh(iv*gv);
        }
    }
}

// ---------------------------------------------------------------------------
// K3: out[b,k] = fc_b[k] + last_f[b,:].fc_w[k,0:64] + hb0[b,:].fc_w[k,64:128]
// ---------------------------------------------------------------------------
__global__ __launch_bounds__(256)
void final_fc_kernel(const float* __restrict__ last_f, const float* __restrict__ hb0,
                     const float* __restrict__ fc_w, const float* __restrict__ fc_b,
                     float* __restrict__ out)
{
    int t = threadIdx.x;
    if (t >= BB*NC) return;
    int b = t / NC, k = t % NC;
    float acc = fc_b[k];
    const float* w = fc_w + k*128;
    #pragma unroll
    for (int j = 0; j < 64; ++j) acc += last_f[b*64+j]*w[j];
    #pragma unroll
    for (int j = 0; j < 64; ++j) acc += hb0[b*64+j]*w[64+j];
    out[b*NC + k] = acc;
}

extern "C" void kernel_launch(void* const* d_in, const int* in_sizes, int n_in,
                              void* d_out, int out_size, void* d_ws, size_t ws_size,
                              hipStream_t stream)
{
    const float* x_real = (const float*)d_in[0];
    const float* x_imag = (const float*)d_in[1];
    const int*   lengths= (const int*)d_in[2];
    const float* c1r_w = (const float*)d_in[3];
    const float* c1r_b = (const float*)d_in[4];
    const float* c1i_w = (const float*)d_in[5];
    const float* c1i_b = (const float*)d_in[6];
    const float* c2r_w = (const float*)d_in[7];
    const float* c2r_b = (const float*)d_in[8];
    const float* c2i_w = (const float*)d_in[9];
    const float* c2i_b = (const float*)d_in[10];
    const float* fus_w = (const float*)d_in[11];
    const float* fus_b = (const float*)d_in[12];
    const float* wf_ih = (const float*)d_in[13];
    const float* wf_hh = (const float*)d_in[14];
    const float* bf_ih = (const float*)d_in[15];
    const float* bf_hh = (const float*)d_in[16];
    const float* wb_ih = (const float*)d_in[17];
    const float* wb_hh = (const float*)d_in[18];
    const float* bb_ih = (const float*)d_in[19];
    const float* bb_hh = (const float*)d_in[20];
    const float* fc_w  = (const float*)d_in[21];
    const float* fc_b  = (const float*)d_in[22];
    float* out = (float*)d_out;

    // ws layout (floats): pool_r[49152] | pool_m[49152] | fusedg[98304] |
    //                     gates_x[393216] | last_f[1024] | hb0[1024]  (~2.4 MB)
    float* ws      = (float*)d_ws;
    float* pool_r  = ws;
    float* pool_m  = pool_r  + BT*C2;
    float* fusedg  = pool_m  + BT*C2;
    float* gates_x = fusedg  + BT*64;
    float* last_f  = gates_x + BT*256;
    float* hb0     = last_f  + BB*LH;

    conv_pool_mfma<<<dim3(BT, 2), 512, 0, stream>>>(
        x_real, x_imag, c1r_w, c1r_b, c1i_w, c1i_b,
        c2r_w, c2r_b, c2i_w, c2i_b, pool_r, pool_m);

    lstm_prep<<<BT, 256, 0, stream>>>(pool_r, pool_m, fus_w, fus_b,
                                      wf_ih, bf_ih, bf_hh, fusedg, gates_x);

    lstm_scan<<<32, 256, 0, stream>>>(gates_x, fusedg, lengths, wf_hh,
                                      wb_ih, bb_ih, bb_hh, last_f, hb0);

    final_fc_kernel<<<1, 256, 0, stream>>>(last_f, hb0, fc_w, fc_b, out);
}